// Round 5
// baseline (2620.040 us; speedup 1.0000x reference)
//
#include <hip/hip_runtime.h>
#include <math.h>

typedef _Float16 half8 __attribute__((ext_vector_type(8)));
typedef _Float16 half4v __attribute__((ext_vector_type(4)));
typedef _Float16 half2v __attribute__((ext_vector_type(2)));
typedef float floatx16 __attribute__((ext_vector_type(16)));

#define TT 20
#define NB 64      // batch per step
#define LL 90
#define DD 64
#define RR 5760    // L*D
#define HH 1024
#define NG 4096    // 4*H
#define KT 6784    // RR + HH
#define CH0 90     // chunks in K-part0 (5760/64)
#define CHT 106    // total 64-half chunks (6784/64)

__device__ __forceinline__ float sigm(float x) { return 1.f / (1.f + expf(-x)); }

// ---------------- fp32 -> fp16 convert (both weight arrays in one launch) ----------------
__global__ __launch_bounds__(256) void k_conv2(const float* __restrict__ s1, _Float16* __restrict__ d1, int n1,
                                               const float* __restrict__ s2, _Float16* __restrict__ d2, int n2) {
    int i = (blockIdx.x * 256 + threadIdx.x) * 4;
    const float* s; _Float16* d;
    if (i < n1) { s = s1 + i; d = d1 + i; }
    else if ((i -= n1) < n2) { s = s2 + i; d = d2 + i; }
    else return;
    const float4 v = *(const float4*)s;
    half4v o;
    o[0] = (_Float16)v.x; o[1] = (_Float16)v.y;
    o[2] = (_Float16)v.z; o[3] = (_Float16)v.w;
    *(half4v*)d = o;
}

// ---------------- init h0, c0 ----------------
__global__ __launch_bounds__(256) void k_init(const float* __restrict__ feat,
        const float* __restrict__ iWh_w, const float* __restrict__ iWh_b,
        const float* __restrict__ iWc_w, const float* __restrict__ iWc_b,
        float* __restrict__ h, float* __restrict__ c, _Float16* __restrict__ h16) {
    __shared__ float f0p[4][DD];
    __shared__ float f0[DD];
    const int b = blockIdx.x, tid = threadIdx.x;
    const int dd = tid & 63, lg = tid >> 6;
    const float* frow = feat + (size_t)(b * TT) * RR;   // t = 0
    float p = 0;
    for (int l = lg; l < LL; l += 4) p += frow[l * DD + dd];
    f0p[lg][dd] = p;
    __syncthreads();
    if (tid < DD) f0[tid] = (f0p[0][tid] + f0p[1][tid] + f0p[2][tid] + f0p[3][tid]) * (1.0f / LL);
    __syncthreads();
    for (int o = tid; o < HH; o += 256) {
        float ah = iWh_b[o], ac = iWc_b[o];
        for (int d0 = 0; d0 < DD; d0 += 4) {
            const float4 wh = *(const float4*)(iWh_w + (size_t)o * DD + d0);
            const float4 wc = *(const float4*)(iWc_w + (size_t)o * DD + d0);
            ah += f0[d0] * wh.x + f0[d0 + 1] * wh.y + f0[d0 + 2] * wh.z + f0[d0 + 3] * wh.w;
            ac += f0[d0] * wc.x + f0[d0 + 1] * wc.y + f0[d0 + 2] * wc.z + f0[d0 + 3] * wc.w;
        }
        const float hv = tanhf(ah), cv = tanhf(ac);
        h[b * HH + o] = hv; c[b * HH + o] = cv;
        h16[b * HH + o] = (_Float16)hv;
    }
}

// ===== fused LSTM cell (step tattn-1, if do_cell) + attention for step tattn =====
// 64 blocks (one per batch b) x 512 threads. Wx-projection folded in (fp32, from
// the feature row already staged in LDS for the visual write).
__global__ __launch_bounds__(512) void k_step(int tattn, int do_cell,
        const float* __restrict__ gpart, const float* __restrict__ b_ih,
        const float* __restrict__ b_hh, float* __restrict__ cbuf,
        _Float16* __restrict__ h16, _Float16* __restrict__ H16,
        const float* __restrict__ h0buf, const float* __restrict__ feat,
        const float* __restrict__ Wx, const float* __restrict__ Wh,
        const float* __restrict__ v, _Float16* __restrict__ V16) {
    __shared__ float sf[RR];           // feature row [90][64] fp32 (23 KB)
    __shared__ float sWx[DD * DD];     // 16 KB
    __shared__ float sh[HH];
    __shared__ float hWhp[8][DD];
    __shared__ float hWh[DD];
    __shared__ float sv[DD];
    __shared__ float ep[LL][8];
    __shared__ float se[128];
    __shared__ float red[128];
    __shared__ float salpha[LL];
    const int b = blockIdx.x, tid = threadIdx.x;
    const int t = tattn;
    if (tid < DD) sv[tid] = v[tid];

    if (t < TT) {
        const float* frow = feat + ((size_t)b * TT + t) * RR;
        for (int e = tid * 4; e < RR; e += 2048)
            *(float4*)(sf + e) = *(const float4*)(frow + e);
        for (int e = tid * 4; e < DD * DD; e += 2048)
            *(float4*)(sWx + e) = *(const float4*)(Wx + e);
    }

    if (do_cell) {
        // ----- cell for step t-1: 2 hidden units per thread, 8 split-K partials -----
        const int j0 = tid * 2;
        float ag[4][2];
#pragma unroll
        for (int g = 0; g < 4; ++g) { ag[g][0] = 0.f; ag[g][1] = 0.f; }
#pragma unroll
        for (int sp = 0; sp < 8; ++sp) {
            const float* P = gpart + ((size_t)sp * NB + b) * NG;
#pragma unroll
            for (int g = 0; g < 4; ++g) {
                const float2 pv = *(const float2*)(P + g * HH + j0);
                ag[g][0] += pv.x; ag[g][1] += pv.y;
            }
        }
#pragma unroll
        for (int g = 0; g < 4; ++g) {
            const float2 bi = *(const float2*)(b_ih + g * HH + j0);
            const float2 bh = *(const float2*)(b_hh + g * HH + j0);
            ag[g][0] += bi.x + bh.x; ag[g][1] += bi.y + bh.y;
        }
        const float2 cold = *(const float2*)(cbuf + (size_t)b * HH + j0);
        float co[2] = { cold.x, cold.y };
        float2 cnew; half2v hh2;
#pragma unroll
        for (int q = 0; q < 2; ++q) {
            const float cv = sigm(ag[1][q]) * co[q] + sigm(ag[0][q]) * tanhf(ag[2][q]);
            const float hv = sigm(ag[3][q]) * tanhf(cv);
            ((float*)&cnew)[q] = cv;
            hh2[q] = (_Float16)hv;
            sh[j0 + q] = hv;
        }
        *(float2*)(cbuf + (size_t)b * HH + j0) = cnew;
        *(half2v*)(h16 + (size_t)b * HH + j0) = hh2;
        *(half2v*)(H16 + ((size_t)(t - 1) * NB + b) * HH + j0) = hh2;
    } else {
        for (int e = tid; e < HH; e += 512) sh[e] = h0buf[(size_t)b * HH + e];
    }
    __syncthreads();
    if (t >= TT) return;

    // ----- hWh = h @ Wh : 8-way K-split, coalesced 256B wave loads (fp32 Wh) -----
    { const int a = tid & 63, q = tid >> 6;           // q in 0..7
      const float* Wq = Wh + (size_t)(q * 128) * DD + a;
      const float* shq = sh + q * 128;
      float p0 = 0.f, p1 = 0.f;
#pragma unroll 8
      for (int k = 0; k < 128; k += 2) {
          p0 += shq[k] * Wq[(size_t)k * DD];
          p1 += shq[k + 1] * Wq[(size_t)(k + 1) * DD];
      }
      hWhp[q][a] = p0 + p1; }
    __syncthreads();
    if (tid < DD) {
        float s = 0.f;
#pragma unroll
        for (int q = 0; q < 8; ++q) s += hWhp[q][tid];
        hWh[tid] = s;
    }
    __syncthreads();

    // ----- e_l = sum_d tanh((x@Wx)_d + hWh_d) * v_d : 720 tasks (l, d-octet) -----
    for (int task = tid; task < LL * 8; task += 512) {
        const int l = task >> 3, d8 = (task & 7) << 3;
        float acc[8];
#pragma unroll
        for (int u = 0; u < 8; ++u) acc[u] = hWh[d8 + u];
        const float* sfl = sf + l * DD;
        for (int k = 0; k < DD; ++k) {
            const float xv = sfl[k];
            const float* wr = sWx + k * DD + d8;
#pragma unroll
            for (int u = 0; u < 8; ++u) acc[u] += xv * wr[u];
        }
        float e = 0.f;
#pragma unroll
        for (int u = 0; u < 8; ++u) e += tanhf(acc[u]) * sv[d8 + u];
        ep[l][task & 7] = e;
    }
    __syncthreads();
    if (tid < LL) {
        float s = 0.f;
#pragma unroll
        for (int q2 = 0; q2 < 8; ++q2) s += ep[tid][q2];
        se[tid] = s;
    } else if (tid < 128) se[tid] = -1e30f;
    __syncthreads();
    if (tid < 128) red[tid] = se[tid];
    __syncthreads();
    for (int s = 64; s; s >>= 1) { if (tid < s) red[tid] = fmaxf(red[tid], red[tid + s]); __syncthreads(); }
    const float mx = red[0];
    __syncthreads();
    float ex = 0.f;
    if (tid < LL) { ex = expf(se[tid] - mx); salpha[tid] = ex; }
    if (tid < 128) red[tid] = ex;
    __syncthreads();
    for (int s = 64; s; s >>= 1) { if (tid < s) red[tid] += red[tid + s]; __syncthreads(); }
    const float inv = 1.f / red[0];
    __syncthreads();
    if (tid < LL) salpha[tid] *= inv;
    __syncthreads();

    // ----- visual write from the LDS-staged feature row -----
    _Float16* vout = V16 + ((size_t)t * NB + b) * RR;
    for (int e = tid * 4; e < RR; e += 2048) {
        const float4 u4 = *(const float4*)(sf + e);
        const float al = salpha[e >> 6];
        half4v o;
        o[0] = (_Float16)(u4.x * al); o[1] = (_Float16)(u4.y * al);
        o[2] = (_Float16)(u4.z * al); o[3] = (_Float16)(u4.w * al);
        *(half4v*)(vout + e) = o;
    }
}

// ================= gates GEMM (split-K=8, XCD-pinned N-tiles) =================
__device__ __forceinline__ void stage_tile(const char* src, size_t stride, char* lds, int ln) {
    const char* g = src + (size_t)(ln >> 3) * stride + (((ln & 7) ^ (ln >> 3)) << 4);
#pragma unroll
    for (int i = 0; i < 8; ++i)
        __builtin_amdgcn_global_load_lds(
            (const __attribute__((address_space(1))) void*)(g + (size_t)(i * 8) * stride),
            (__attribute__((address_space(3))) void*)(lds + i * 1024), 16, 0, 0);
}

struct Src2 { const char* p0; size_t s0; const char* p1; size_t s1; };

__device__ __forceinline__ const char* chunk_ptr(const Src2& s, int c, size_t& stride) {
    if (c < CH0) { stride = s.s0; return s.p0 + (size_t)c * 128; }
    stride = s.s1; return s.p1 + (size_t)(c - CH0) * 128;
}

// grid = 512 blocks x 128 thr. kb = bid>>6 (split-K 0..7);
// nt = ((bid&7)<<3)|((bid>>3)&7): the 8 nt-tiles sharing an XCD (bid%8) are
// consecutive -> each XCD's L2 re-serves the same ~7MB weight slice every step.
__global__ __launch_bounds__(128) void k_gates(int t, const _Float16* __restrict__ V16,
        const _Float16* __restrict__ h16, const _Float16* __restrict__ Wih,
        const _Float16* __restrict__ Whh, float* __restrict__ gpart) {
    __shared__ char smem[65536];
    const int bid = blockIdx.x;
    const int kb = bid >> 6;
    const int nt = ((bid & 7) << 3) | ((bid >> 3) & 7);
    const int tid = threadIdx.x, w = tid >> 6, ln = tid & 63;
    char* wlds = smem + w * 32768;

    const _Float16* Vt = V16 + (size_t)t * NB * RR;
    Src2 As = { (const char*)Vt, (size_t)RR * 2, (const char*)h16, (size_t)HH * 2 };
    Src2 Bs = { (const char*)(Wih + (size_t)(nt * 64) * RR), (size_t)RR * 2,
                (const char*)(Whh + (size_t)(nt * 64) * HH), (size_t)HH * 2 };

    floatx16 acc00, acc01, acc10, acc11;
#pragma unroll
    for (int i = 0; i < 16; ++i) { acc00[i] = 0.f; acc01[i] = 0.f; acc10[i] = 0.f; acc11[i] = 0.f; }

    const int start = kb * 2 + w;     // residues 0..15 mod 16 across kb,w
    const int r = ln & 31;
    const int xsw = (r & 7) << 4;
    const int fo = (ln >> 5) * 16;
    const int rbyte = r * 128;

    int c = start, bsel = 0;
    { size_t st; const char* p = chunk_ptr(As, c, st); stage_tile(p, st, wlds, ln);
      p = chunk_ptr(Bs, c, st); stage_tile(p, st, wlds + 8192, ln); }
    while (true) {
        const int cn = c + 16;
        if (cn < CHT) {
            char* nl = wlds + ((bsel ^ 1) << 14);
            size_t st; const char* p = chunk_ptr(As, cn, st); stage_tile(p, st, nl, ln);
            p = chunk_ptr(Bs, cn, st); stage_tile(p, st, nl + 8192, ln);
            asm volatile("s_waitcnt vmcnt(16)" ::: "memory");
        } else {
            asm volatile("s_waitcnt vmcnt(0)" ::: "memory");
        }
        __builtin_amdgcn_sched_barrier(0);
        const char* LA = wlds + (bsel << 14);
        const char* LB = LA + 8192;
#pragma unroll
        for (int kk = 0; kk < 4; ++kk) {
            const int o = ((kk * 32 + fo) ^ xsw);
            const half8 a0 = *(const half8*)(LA + rbyte + o);
            const half8 a1 = *(const half8*)(LA + 4096 + rbyte + o);
            const half8 b0 = *(const half8*)(LB + rbyte + o);
            const half8 b1 = *(const half8*)(LB + 4096 + rbyte + o);
            acc00 = __builtin_amdgcn_mfma_f32_32x32x16_f16(a0, b0, acc00, 0, 0, 0);
            acc01 = __builtin_amdgcn_mfma_f32_32x32x16_f16(a0, b1, acc01, 0, 0, 0);
            acc10 = __builtin_amdgcn_mfma_f32_32x32x16_f16(a1, b0, acc10, 0, 0, 0);
            acc11 = __builtin_amdgcn_mfma_f32_32x32x16_f16(a1, b1, acc11, 0, 0, 0);
        }
        if (cn >= CHT) break;
        c = cn; bsel ^= 1;
    }
    __syncthreads();
    float* Rg = (float*)(smem + w * 16384);
    const int rbase = 4 * (ln >> 5), lr = ln & 31;
#pragma unroll
    for (int q = 0; q < 16; ++q) {
        const int row = rbase + (q & 3) + 8 * (q >> 2);
        Rg[row * 64 + lr]             = acc00[q];
        Rg[row * 64 + 32 + lr]        = acc01[q];
        Rg[(row + 32) * 64 + lr]      = acc10[q];
        Rg[(row + 32) * 64 + 32 + lr] = acc11[q];
    }
    __syncthreads();
    const float* R0 = (const float*)smem;
    const float* R1 = (const float*)(smem + 16384);
    float* Cout = gpart + (size_t)kb * (NB * NG);
    for (int e = tid * 4; e < 4096; e += 512) {
        const float4 u = *(const float4*)(R0 + e);
        const float4 v2 = *(const float4*)(R1 + e);
        float4 s2; s2.x = u.x + v2.x; s2.y = u.y + v2.y; s2.z = u.z + v2.z; s2.w = u.w + v2.w;
        const int row = e >> 6, col = e & 63;
        *(float4*)(Cout + (size_t)row * NG + nt * 64 + col) = s2;
    }
}

// ===== Wu-fused head weights: Wyu16[j][0:6784] = Wu @ [Wy | Whw], cst[j] =====
__global__ __launch_bounds__(256) void k_wfuse(const float* __restrict__ Wy,
        const float* __restrict__ Whw, const float* __restrict__ Wu,
        const float* __restrict__ Whb, const float* __restrict__ Wub,
        _Float16* __restrict__ Wyu16, float* __restrict__ cst) {
    __shared__ float sWu[3 * HH];
    __shared__ float part[4][3][64];
    const int tid = threadIdx.x;
    for (int e = tid * 4; e < 3 * HH; e += 1024)
        *(float4*)(sWu + e) = *(const float4*)(Wu + e);
    __syncthreads();
    if (blockIdx.x == CHT) {   // cst block
        float a0 = 0, a1 = 0, a2 = 0;
        for (int m = tid; m < HH; m += 256) {
            const float wb = Whb[m];
            a0 += sWu[m] * wb; a1 += sWu[HH + m] * wb; a2 += sWu[2 * HH + m] * wb;
        }
        __shared__ float rp[3][256];
        rp[0][tid] = a0; rp[1][tid] = a1; rp[2][tid] = a2;
        __syncthreads();
        for (int s = 128; s; s >>= 1) {
            if (tid < s) { rp[0][tid] += rp[0][tid + s]; rp[1][tid] += rp[1][tid + s]; rp[2][tid] += rp[2][tid + s]; }
            __syncthreads();
        }
        if (tid < 3) cst[tid] = rp[tid][0] + Wub[tid];
        return;
    }
    const int kk = tid & 63, qm = tid >> 6;
    const int k = blockIdx.x * 64 + kk;
    const float* src; size_t ld;
    if (blockIdx.x < CH0) { src = Wy + k; ld = RR; }
    else { src = Whw + (k - RR); ld = HH; }
    float a0 = 0, a1 = 0, a2 = 0;
    for (int m = qm * 256; m < qm * 256 + 256; ++m) {
        const float val = src[(size_t)m * ld];
        a0 += sWu[m] * val; a1 += sWu[HH + m] * val; a2 += sWu[2 * HH + m] * val;
    }
    part[qm][0][kk] = a0; part[qm][1][kk] = a1; part[qm][2][kk] = a2;
    __syncthreads();
    if (tid < 192) {
        const int j = tid >> 6, k2 = tid & 63;
        const float s = part[0][j][k2] + part[1][j][k2] + part[2][j][k2] + part[3][j][k2];
        Wyu16[(size_t)j * KT + blockIdx.x * 64 + k2] = (_Float16)s;
    }
}

// ===== final: out[r][j] = V16[r].Wyu[j][:5760] + H16[r].Wyu[j][5760:] + cst[j] =====
__global__ __launch_bounds__(256) void k_final2(const _Float16* __restrict__ V16,
        const _Float16* __restrict__ H16, const _Float16* __restrict__ Wyu,
        const float* __restrict__ cst, float* __restrict__ out) {
    __shared__ float rp[4][3];
    const int r = blockIdx.x, tid = threadIdx.x;   // r = t*64 + b
    const _Float16* vrow = V16 + (size_t)r * RR;
    const _Float16* hrow = H16 + (size_t)r * HH;
    float a0 = 0, a1 = 0, a2 = 0;
    for (int e = tid * 8; e < KT; e += 2048) {
        half8 x;
        if (e < RR) x = *(const half8*)(vrow + e);
        else        x = *(const half8*)(hrow + (e - RR));
        const half8 w0 = *(const half8*)(Wyu + e);
        const half8 w1 = *(const half8*)(Wyu + KT + e);
        const half8 w2 = *(const half8*)(Wyu + 2 * KT + e);
#pragma unroll
        for (int i = 0; i < 8; ++i) {
            const float xv = (float)x[i];
            a0 += xv * (float)w0[i]; a1 += xv * (float)w1[i]; a2 += xv * (float)w2[i];
        }
    }
    for (int o = 32; o > 0; o >>= 1) {
        a0 += __shfl_down(a0, o, 64); a1 += __shfl_down(a1, o, 64); a2 += __shfl_down(a2, o, 64);
    }
    const int wv = tid >> 6;
    if ((tid & 63) == 0) { rp[wv][0] = a0; rp[wv][1] = a1; rp[wv][2] = a2; }
    __syncthreads();
    if (tid < 3) {
        const float x = rp[0][tid] + rp[1][tid] + rp[2][tid] + rp[3][tid] + cst[tid];
        const int b = r & 63, ts = r >> 6;
        out[((size_t)b * TT + ts) * 3 + tid] = x;
    }
}

extern "C" void kernel_launch(void* const* d_in, const int* in_sizes, int n_in,
                              void* d_out, int out_size, void* d_ws, size_t ws_size,
                              hipStream_t stream) {
    (void)in_sizes; (void)n_in; (void)out_size;
    const float* feature = (const float*)d_in[0];
    const float* attn_Wx = (const float*)d_in[1];
    const float* attn_Wh = (const float*)d_in[2];
    const float* attn_v  = (const float*)d_in[3];
    const float* W_ih    = (const float*)d_in[4];
    const float* W_hh    = (const float*)d_in[5];
    const float* b_ih    = (const float*)d_in[6];
    const float* b_hh    = (const float*)d_in[7];
    const float* Wh_w    = (const float*)d_in[8];
    const float* Wh_b    = (const float*)d_in[9];
    const float* Wy_w    = (const float*)d_in[10];
    const float* Wu_w    = (const float*)d_in[11];
    const float* Wu_b    = (const float*)d_in[12];
    const float* iWh_w   = (const float*)d_in[13];
    const float* iWh_b   = (const float*)d_in[14];
    const float* iWc_w   = (const float*)d_in[15];
    const float* iWc_b   = (const float*)d_in[16];
    float* out = (float*)d_out;

    char* ws = (char*)d_ws;
    size_t off = 0;
    auto alloc = [&](size_t bytes) { void* p = ws + off; off += (bytes + 255) & ~(size_t)255; return p; };
    _Float16* Wih16 = (_Float16*)alloc((size_t)NG * RR * 2);
    _Float16* Whh16 = (_Float16*)alloc((size_t)NG * HH * 2);
    _Float16* V16   = (_Float16*)alloc((size_t)TT * NB * RR * 2);
    _Float16* H16   = (_Float16*)alloc((size_t)TT * NB * HH * 2);
    float*    hbuf  = (float*)alloc((size_t)NB * HH * 4);
    float*    cbuf  = (float*)alloc((size_t)NB * HH * 4);
    _Float16* h16   = (_Float16*)alloc((size_t)NB * HH * 2);
    float*    gpart = (float*)alloc((size_t)8 * NB * NG * 4);
    _Float16* Wyu16 = (_Float16*)alloc((size_t)3 * KT * 2);
    float*    cstb  = (float*)alloc(16);
    if (ws_size < off) return;   // refuse to scribble out of bounds

    // one-time: weight conversion + head-weight fusion + init
    const int nconv = NG * RR + NG * HH;
    k_conv2<<<(nconv / 4 + 255) / 256, 256, 0, stream>>>(W_ih, Wih16, NG * RR,
                                                         W_hh, Whh16, NG * HH);
    k_wfuse<<<CHT + 1, 256, 0, stream>>>(Wy_w, Wh_w, Wu_w, Wh_b, Wu_b, Wyu16, cstb);
    k_init<<<64, 256, 0, stream>>>(feature, iWh_w, iWh_b, iWc_w, iWc_b, hbuf, cbuf, h16);

    // attention for t=0 from h0
    k_step<<<64, 512, 0, stream>>>(0, 0, gpart, b_ih, b_hh, cbuf, h16, H16, hbuf,
                                   feature, attn_Wx, attn_Wh, attn_v, V16);
    for (int t = 0; t < TT; ++t) {
        k_gates<<<512, 128, 0, stream>>>(t, V16, h16, Wih16, Whh16, gpart);
        k_step<<<64, 512, 0, stream>>>(t + 1, 1, gpart, b_ih, b_hh, cbuf, h16, H16, hbuf,
                                       feature, attn_Wx, attn_Wh, attn_v, V16);
    }

    k_final2<<<1280, 256, 0, stream>>>(V16, H16, Wyu16, cstb, out);
}

// Round 6
// 649.529 us; speedup vs baseline: 4.0338x; 4.0338x over previous
//
#include <hip/hip_runtime.h>
#include <math.h>

typedef _Float16 half8 __attribute__((ext_vector_type(8)));
typedef _Float16 half4v __attribute__((ext_vector_type(4)));
typedef _Float16 half2v __attribute__((ext_vector_type(2)));
typedef float floatx16 __attribute__((ext_vector_type(16)));

#define TT 20
#define NB 64      // batch per step
#define LL 90
#define DD 64
#define RR 5760    // L*D
#define HH 1024
#define NG 4096    // 4*H
#define KT 6784    // RR + HH
#define CH0 90     // chunks in K-part0 (5760/64)
#define CHT 106    // total 64-half chunks (6784/64)

__device__ __forceinline__ float sigm(float x) { return 1.f / (1.f + expf(-x)); }

// ---------------- fp32 -> fp16 convert (both weight arrays in one launch) ----------------
__global__ __launch_bounds__(256) void k_conv2(const float* __restrict__ s1, _Float16* __restrict__ d1, int n1,
                                               const float* __restrict__ s2, _Float16* __restrict__ d2, int n2) {
    int i = (blockIdx.x * 256 + threadIdx.x) * 4;
    const float* s; _Float16* d;
    if (i < n1) { s = s1 + i; d = d1 + i; }
    else if ((i -= n1) < n2) { s = s2 + i; d = d2 + i; }
    else return;
    const float4 v = *(const float4*)s;
    half4v o;
    o[0] = (_Float16)v.x; o[1] = (_Float16)v.y;
    o[2] = (_Float16)v.z; o[3] = (_Float16)v.w;
    *(half4v*)d = o;
}

// ---------------- transpose attn_Wh [1024][64] fp32 -> WhT16 [64][1024] fp16 ----------------
__global__ __launch_bounds__(256) void k_whT(const float* __restrict__ Wh, _Float16* __restrict__ WhT) {
    const int idx = blockIdx.x * 256 + threadIdx.x;   // 0..16383
    const int a = idx >> 8, k4 = (idx & 255) * 4;
    half4v o;
#pragma unroll
    for (int u = 0; u < 4; ++u) o[u] = (_Float16)Wh[(size_t)(k4 + u) * DD + a];
    *(half4v*)(WhT + (size_t)a * HH + k4) = o;
}

// ---------------- xproj = feature @ attn_Wx  -> fp16 [1280][90][64] ----------------
__global__ __launch_bounds__(256) void k_xproj(const float* __restrict__ feat,
                                               const float* __restrict__ Wx,
                                               _Float16* __restrict__ xp) {
    __shared__ float sWx[DD * DD];
    __shared__ float sx[16 * DD];
    const int row = blockIdx.x;            // 0..1279  (= b*TT + t)
    const int tid = threadIdx.x;
    for (int e = tid * 4; e < DD * DD; e += 1024)
        *(float4*)(sWx + e) = *(const float4*)(Wx + e);
    const int a4 = tid & 15, lg = tid >> 4;
    const float* frow = feat + (size_t)row * RR;
    for (int lb = 0; lb < LL; lb += 16) {
        __syncthreads();
        { int e = tid * 4; int ls = e >> 6, dd = e & 63;
          if (lb + ls < LL) *(float4*)(sx + e) = *(const float4*)(frow + (lb + ls) * DD + dd); }
        __syncthreads();
        const int l = lb + lg;
        if (l < LL) {
            float a0 = 0, a1 = 0, a2 = 0, a3 = 0;
            for (int dd = 0; dd < DD; ++dd) {
                const float xv = sx[lg * DD + dd];
                const float4 wv = *(const float4*)(sWx + dd * DD + a4 * 4);
                a0 += xv * wv.x; a1 += xv * wv.y; a2 += xv * wv.z; a3 += xv * wv.w;
            }
            half4v o;
            o[0] = (_Float16)a0; o[1] = (_Float16)a1; o[2] = (_Float16)a2; o[3] = (_Float16)a3;
            *(half4v*)(xp + (size_t)row * RR + l * DD + a4 * 4) = o;
        }
    }
}

// ---------------- init h0, c0 ----------------
__global__ __launch_bounds__(256) void k_init(const float* __restrict__ feat,
        const float* __restrict__ iWh_w, const float* __restrict__ iWh_b,
        const float* __restrict__ iWc_w, const float* __restrict__ iWc_b,
        float* __restrict__ h, float* __restrict__ c, _Float16* __restrict__ h16) {
    __shared__ float f0p[4][DD];
    __shared__ float f0[DD];
    const int b = blockIdx.x, tid = threadIdx.x;
    const int dd = tid & 63, lg = tid >> 6;
    const float* frow = feat + (size_t)(b * TT) * RR;   // t = 0
    float p = 0;
    for (int l = lg; l < LL; l += 4) p += frow[l * DD + dd];
    f0p[lg][dd] = p;
    __syncthreads();
    if (tid < DD) f0[tid] = (f0p[0][tid] + f0p[1][tid] + f0p[2][tid] + f0p[3][tid]) * (1.0f / LL);
    __syncthreads();
    for (int o = tid; o < HH; o += 256) {
        float ah = iWh_b[o], ac = iWc_b[o];
        for (int d0 = 0; d0 < DD; d0 += 4) {
            const float4 wh = *(const float4*)(iWh_w + (size_t)o * DD + d0);
            const float4 wc = *(const float4*)(iWc_w + (size_t)o * DD + d0);
            ah += f0[d0] * wh.x + f0[d0 + 1] * wh.y + f0[d0 + 2] * wh.z + f0[d0 + 3] * wh.w;
            ac += f0[d0] * wc.x + f0[d0 + 1] * wc.y + f0[d0 + 2] * wc.z + f0[d0 + 3] * wc.w;
        }
        const float hv = tanhf(ah), cv = tanhf(ac);
        h[b * HH + o] = hv; c[b * HH + o] = cv;
        h16[b * HH + o] = (_Float16)hv;
    }
}

// ===== fused LSTM cell (step tattn-1, if do_cell) + attention for step tattn =====
// grid (64, 4): blockIdx.x = batch b; blockIdx.y = qv quarter (splits V write).
// Cell/hWh/softmax computed redundantly in the 4 qv blocks (bit-identical fp32
// math -> benign same-value races; c ping-pongs cin->cout so no RW hazard).
__global__ __launch_bounds__(512) void k_step(int tattn, int do_cell,
        const float* __restrict__ gpart, const float* __restrict__ b_ih,
        const float* __restrict__ b_hh, const float* __restrict__ cin,
        float* __restrict__ cout, _Float16* __restrict__ h16,
        _Float16* __restrict__ H16, const float* __restrict__ h0buf,
        const float* __restrict__ feat, const _Float16* __restrict__ xp,
        const _Float16* __restrict__ WhT, const float* __restrict__ v,
        _Float16* __restrict__ V16) {
    __shared__ float sh[HH];
    __shared__ float hWhp[8][DD];
    __shared__ float hWh[DD];
    __shared__ float sv[DD];
    __shared__ float ep[LL][4];
    __shared__ float se[128];
    __shared__ float red[128];
    __shared__ float salpha[LL];
    const int b = blockIdx.x, qv = blockIdx.y, tid = threadIdx.x;
    const int t = tattn;
    if (tid < DD) sv[tid] = v[tid];

    if (do_cell) {
        // ----- cell for step t-1: 2 hidden units per thread, 8 split-K partials -----
        const int j0 = tid * 2;
        float ag[4][2];
#pragma unroll
        for (int g = 0; g < 4; ++g) { ag[g][0] = 0.f; ag[g][1] = 0.f; }
#pragma unroll
        for (int sp = 0; sp < 8; ++sp) {
            const float* P = gpart + ((size_t)sp * NB + b) * NG;
#pragma unroll
            for (int g = 0; g < 4; ++g) {
                const float2 pv = *(const float2*)(P + g * HH + j0);
                ag[g][0] += pv.x; ag[g][1] += pv.y;
            }
        }
#pragma unroll
        for (int g = 0; g < 4; ++g) {
            const float2 bi = *(const float2*)(b_ih + g * HH + j0);
            const float2 bh = *(const float2*)(b_hh + g * HH + j0);
            ag[g][0] += bi.x + bh.x; ag[g][1] += bi.y + bh.y;
        }
        const float2 cold = *(const float2*)(cin + (size_t)b * HH + j0);
        float co[2] = { cold.x, cold.y };
        float2 cnew; half2v hh2;
#pragma unroll
        for (int q = 0; q < 2; ++q) {
            const float cv = sigm(ag[1][q]) * co[q] + sigm(ag[0][q]) * tanhf(ag[2][q]);
            const float hv = sigm(ag[3][q]) * tanhf(cv);
            ((float*)&cnew)[q] = cv;
            hh2[q] = (_Float16)hv;
            sh[j0 + q] = hv;
        }
        *(float2*)(cout + (size_t)b * HH + j0) = cnew;
        *(half2v*)(h16 + (size_t)b * HH + j0) = hh2;
        *(half2v*)(H16 + ((size_t)(t - 1) * NB + b) * HH + j0) = hh2;
    } else {
        for (int e = tid; e < HH; e += 512) sh[e] = h0buf[(size_t)b * HH + e];
    }
    __syncthreads();
    if (t >= TT) return;

    // ----- hWh = h @ Wh via transposed fp16 WhT[64][1024]: contiguous reads -----
    { const int a = tid & 63, q8 = tid >> 6;          // q8 in 0..7
      const _Float16* Wq = WhT + (size_t)a * HH + q8 * 128;
      const float* shq = sh + q8 * 128;
      float p = 0.f;
#pragma unroll
      for (int k = 0; k < 128; k += 8) {
          const half8 wv = *(const half8*)(Wq + k);
#pragma unroll
          for (int u = 0; u < 8; ++u) p += shq[k + u] * (float)wv[u];
      }
      hWhp[q8][a] = p; }
    __syncthreads();
    if (tid < DD) {
        float s = 0.f;
#pragma unroll
        for (int q = 0; q < 8; ++q) s += hWhp[q][tid];
        hWh[tid] = s;
    }
    __syncthreads();

    // ----- e_l = sum_d tanh(xp + hWh) * v : 360 tasks (l, quarter) -----
    const size_t frow = (size_t)(b * TT + t) * RR;
    if (tid < 360) {
        const int l = tid >> 2, qq = tid & 3;
        const _Float16* xr = xp + frow + l * DD + qq * 16;
        const half8 x0 = *(const half8*)(xr);
        const half8 x1 = *(const half8*)(xr + 8);
        float acc = 0.f;
#pragma unroll
        for (int i = 0; i < 8; ++i)
            acc += tanhf((float)x0[i] + hWh[qq * 16 + i]) * sv[qq * 16 + i];
#pragma unroll
        for (int i = 0; i < 8; ++i)
            acc += tanhf((float)x1[i] + hWh[qq * 16 + 8 + i]) * sv[qq * 16 + 8 + i];
        ep[l][qq] = acc;
    }
    __syncthreads();
    if (tid < LL) se[tid] = ep[tid][0] + ep[tid][1] + ep[tid][2] + ep[tid][3];
    else if (tid < 128) se[tid] = -1e30f;
    __syncthreads();
    if (tid < 128) red[tid] = se[tid];
    __syncthreads();
    for (int s = 64; s; s >>= 1) { if (tid < s) red[tid] = fmaxf(red[tid], red[tid + s]); __syncthreads(); }
    const float mx = red[0];
    __syncthreads();
    float ex = 0.f;
    if (tid < LL) { ex = expf(se[tid] - mx); salpha[tid] = ex; }
    if (tid < 128) red[tid] = ex;
    __syncthreads();
    for (int s = 64; s; s >>= 1) { if (tid < s) red[tid] += red[tid + s]; __syncthreads(); }
    const float inv = 1.f / red[0];
    __syncthreads();
    if (tid < LL) salpha[tid] *= inv;
    __syncthreads();

    // ----- visual write: this block writes quarter qv (1440 floats) -----
    _Float16* vout = V16 + ((size_t)t * NB + b) * RR;
    const float* fr = feat + frow;
    const int ebeg = qv * 1440;
    const int e = ebeg + tid * 4;
    if (e < ebeg + 1440) {
        const float4 u4 = *(const float4*)(fr + e);
        const float al = salpha[e >> 6];
        half4v o;
        o[0] = (_Float16)(u4.x * al); o[1] = (_Float16)(u4.y * al);
        o[2] = (_Float16)(u4.z * al); o[3] = (_Float16)(u4.w * al);
        *(half4v*)(vout + e) = o;
    }
}

// ================= gates GEMM (split-K=8, XCD-pinned N-tiles) =================
__device__ __forceinline__ void stage_tile(const char* src, size_t stride, char* lds, int ln) {
    const char* g = src + (size_t)(ln >> 3) * stride + (((ln & 7) ^ (ln >> 3)) << 4);
#pragma unroll
    for (int i = 0; i < 8; ++i)
        __builtin_amdgcn_global_load_lds(
            (const __attribute__((address_space(1))) void*)(g + (size_t)(i * 8) * stride),
            (__attribute__((address_space(3))) void*)(lds + i * 1024), 16, 0, 0);
}

struct Src2 { const char* p0; size_t s0; const char* p1; size_t s1; };

__device__ __forceinline__ const char* chunk_ptr(const Src2& s, int c, size_t& stride) {
    if (c < CH0) { stride = s.s0; return s.p0 + (size_t)c * 128; }
    stride = s.s1; return s.p1 + (size_t)(c - CH0) * 128;
}

// grid = 512 blocks x 128 thr. kb = bid>>6 (split-K 0..7);
// nt = ((bid&7)<<3)|((bid>>3)&7): XCD-pinned weight slices.
__global__ __launch_bounds__(128) void k_gates(int t, const _Float16* __restrict__ V16,
        const _Float16* __restrict__ h16, const _Float16* __restrict__ Wih,
        const _Float16* __restrict__ Whh, float* __restrict__ gpart) {
    __shared__ char smem[65536];
    const int bid = blockIdx.x;
    const int kb = bid >> 6;
    const int nt = ((bid & 7) << 3) | ((bid >> 3) & 7);
    const int tid = threadIdx.x, w = tid >> 6, ln = tid & 63;
    char* wlds = smem + w * 32768;

    const _Float16* Vt = V16 + (size_t)t * NB * RR;
    Src2 As = { (const char*)Vt, (size_t)RR * 2, (const char*)h16, (size_t)HH * 2 };
    Src2 Bs = { (const char*)(Wih + (size_t)(nt * 64) * RR), (size_t)RR * 2,
                (const char*)(Whh + (size_t)(nt * 64) * HH), (size_t)HH * 2 };

    floatx16 acc00, acc01, acc10, acc11;
#pragma unroll
    for (int i = 0; i < 16; ++i) { acc00[i] = 0.f; acc01[i] = 0.f; acc10[i] = 0.f; acc11[i] = 0.f; }

    const int start = kb * 2 + w;     // residues 0..15 mod 16 across kb,w
    const int r = ln & 31;
    const int xsw = (r & 7) << 4;
    const int fo = (ln >> 5) * 16;
    const int rbyte = r * 128;

    int c = start, bsel = 0;
    { size_t st; const char* p = chunk_ptr(As, c, st); stage_tile(p, st, wlds, ln);
      p = chunk_ptr(Bs, c, st); stage_tile(p, st, wlds + 8192, ln); }
    while (true) {
        const int cn = c + 16;
        if (cn < CHT) {
            char* nl = wlds + ((bsel ^ 1) << 14);
            size_t st; const char* p = chunk_ptr(As, cn, st); stage_tile(p, st, nl, ln);
            p = chunk_ptr(Bs, cn, st); stage_tile(p, st, nl + 8192, ln);
            asm volatile("s_waitcnt vmcnt(16)" ::: "memory");
        } else {
            asm volatile("s_waitcnt vmcnt(0)" ::: "memory");
        }
        __builtin_amdgcn_sched_barrier(0);
        const char* LA = wlds + (bsel << 14);
        const char* LB = LA + 8192;
#pragma unroll
        for (int kk = 0; kk < 4; ++kk) {
            const int o = ((kk * 32 + fo) ^ xsw);
            const half8 a0 = *(const half8*)(LA + rbyte + o);
            const half8 a1 = *(const half8*)(LA + 4096 + rbyte + o);
            const half8 b0 = *(const half8*)(LB + rbyte + o);
            const half8 b1 = *(const half8*)(LB + 4096 + rbyte + o);
            acc00 = __builtin_amdgcn_mfma_f32_32x32x16_f16(a0, b0, acc00, 0, 0, 0);
            acc01 = __builtin_amdgcn_mfma_f32_32x32x16_f16(a0, b1, acc01, 0, 0, 0);
            acc10 = __builtin_amdgcn_mfma_f32_32x32x16_f16(a1, b0, acc10, 0, 0, 0);
            acc11 = __builtin_amdgcn_mfma_f32_32x32x16_f16(a1, b1, acc11, 0, 0, 0);
        }
        if (cn >= CHT) break;
        c = cn; bsel ^= 1;
    }
    __syncthreads();
    float* Rg = (float*)(smem + w * 16384);
    const int rbase = 4 * (ln >> 5), lr = ln & 31;
#pragma unroll
    for (int q = 0; q < 16; ++q) {
        const int row = rbase + (q & 3) + 8 * (q >> 2);
        Rg[row * 64 + lr]             = acc00[q];
        Rg[row * 64 + 32 + lr]        = acc01[q];
        Rg[(row + 32) * 64 + lr]      = acc10[q];
        Rg[(row + 32) * 64 + 32 + lr] = acc11[q];
    }
    __syncthreads();
    const float* R0 = (const float*)smem;
    const float* R1 = (const float*)(smem + 16384);
    float* Cout = gpart + (size_t)kb * (NB * NG);
    for (int e = tid * 4; e < 4096; e += 512) {
        const float4 u = *(const float4*)(R0 + e);
        const float4 v2 = *(const float4*)(R1 + e);
        float4 s2; s2.x = u.x + v2.x; s2.y = u.y + v2.y; s2.z = u.z + v2.z; s2.w = u.w + v2.w;
        const int row = e >> 6, col = e & 63;
        *(float4*)(Cout + (size_t)row * NG + nt * 64 + col) = s2;
    }
}

// ===== Wu-fused head weights: Wyu16[j][0:6784] = Wu @ [Wy | Whw], cst[j] =====
__global__ __launch_bounds__(256) void k_wfuse(const float* __restrict__ Wy,
        const float* __restrict__ Whw, const float* __restrict__ Wu,
        const float* __restrict__ Whb, const float* __restrict__ Wub,
        _Float16* __restrict__ Wyu16, float* __restrict__ cst) {
    __shared__ float sWu[3 * HH];
    __shared__ float part[4][3][64];
    const int tid = threadIdx.x;
    for (int e = tid * 4; e < 3 * HH; e += 1024)
        *(float4*)(sWu + e) = *(const float4*)(Wu + e);
    __syncthreads();
    if (blockIdx.x == CHT) {   // cst block
        float a0 = 0, a1 = 0, a2 = 0;
        for (int m = tid; m < HH; m += 256) {
            const float wb = Whb[m];
            a0 += sWu[m] * wb; a1 += sWu[HH + m] * wb; a2 += sWu[2 * HH + m] * wb;
        }
        __shared__ float rp[3][256];
        rp[0][tid] = a0; rp[1][tid] = a1; rp[2][tid] = a2;
        __syncthreads();
        for (int s = 128; s; s >>= 1) {
            if (tid < s) { rp[0][tid] += rp[0][tid + s]; rp[1][tid] += rp[1][tid + s]; rp[2][tid] += rp[2][tid + s]; }
            __syncthreads();
        }
        if (tid < 3) cst[tid] = rp[tid][0] + Wub[tid];
        return;
    }
    const int kk = tid & 63, qm = tid >> 6;
    const int k = blockIdx.x * 64 + kk;
    const float* src; size_t ld;
    if (blockIdx.x < CH0) { src = Wy + k; ld = RR; }
    else { src = Whw + (k - RR); ld = HH; }
    float a0 = 0, a1 = 0, a2 = 0;
    for (int m = qm * 256; m < qm * 256 + 256; ++m) {
        const float val = src[(size_t)m * ld];
        a0 += sWu[m] * val; a1 += sWu[HH + m] * val; a2 += sWu[2 * HH + m] * val;
    }
    part[qm][0][kk] = a0; part[qm][1][kk] = a1; part[qm][2][kk] = a2;
    __syncthreads();
    if (tid < 192) {
        const int j = tid >> 6, k2 = tid & 63;
        const float s = part[0][j][k2] + part[1][j][k2] + part[2][j][k2] + part[3][j][k2];
        Wyu16[(size_t)j * KT + blockIdx.x * 64 + k2] = (_Float16)s;
    }
}

// ===== final: out[r][j] = V16[r].Wyu[j][:5760] + H16[r].Wyu[j][5760:] + cst[j] =====
__global__ __launch_bounds__(256) void k_final2(const _Float16* __restrict__ V16,
        const _Float16* __restrict__ H16, const _Float16* __restrict__ Wyu,
        const float* __restrict__ cst, float* __restrict__ out) {
    __shared__ float rp[4][3];
    const int r = blockIdx.x, tid = threadIdx.x;   // r = t*64 + b
    const _Float16* vrow = V16 + (size_t)r * RR;
    const _Float16* hrow = H16 + (size_t)r * HH;
    float a0 = 0, a1 = 0, a2 = 0;
    for (int e = tid * 8; e < KT; e += 2048) {
        half8 x;
        if (e < RR) x = *(const half8*)(vrow + e);
        else        x = *(const half8*)(hrow + (e - RR));
        const half8 w0 = *(const half8*)(Wyu + e);
        const half8 w1 = *(const half8*)(Wyu + KT + e);
        const half8 w2 = *(const half8*)(Wyu + 2 * KT + e);
#pragma unroll
        for (int i = 0; i < 8; ++i) {
            const float xv = (float)x[i];
            a0 += xv * (float)w0[i]; a1 += xv * (float)w1[i]; a2 += xv * (float)w2[i];
        }
    }
    for (int o = 32; o > 0; o >>= 1) {
        a0 += __shfl_down(a0, o, 64); a1 += __shfl_down(a1, o, 64); a2 += __shfl_down(a2, o, 64);
    }
    const int wv = tid >> 6;
    if ((tid & 63) == 0) { rp[wv][0] = a0; rp[wv][1] = a1; rp[wv][2] = a2; }
    __syncthreads();
    if (tid < 3) {
        const float x = rp[0][tid] + rp[1][tid] + rp[2][tid] + rp[3][tid] + cst[tid];
        const int b = r & 63, ts = r >> 6;
        out[((size_t)b * TT + ts) * 3 + tid] = x;
    }
}

extern "C" void kernel_launch(void* const* d_in, const int* in_sizes, int n_in,
                              void* d_out, int out_size, void* d_ws, size_t ws_size,
                              hipStream_t stream) {
    (void)in_sizes; (void)n_in; (void)out_size;
    const float* feature = (const float*)d_in[0];
    const float* attn_Wx = (const float*)d_in[1];
    const float* attn_Wh = (const float*)d_in[2];
    const float* attn_v  = (const float*)d_in[3];
    const float* W_ih    = (const float*)d_in[4];
    const float* W_hh    = (const float*)d_in[5];
    const float* b_ih    = (const float*)d_in[6];
    const float* b_hh    = (const float*)d_in[7];
    const float* Wh_w    = (const float*)d_in[8];
    const float* Wh_b    = (const float*)d_in[9];
    const float* Wy_w    = (const float*)d_in[10];
    const float* Wu_w    = (const float*)d_in[11];
    const float* Wu_b    = (const float*)d_in[12];
    const float* iWh_w   = (const float*)d_in[13];
    const float* iWh_b   = (const float*)d_in[14];
    const float* iWc_w   = (const float*)d_in[15];
    const float* iWc_b   = (const float*)d_in[16];
    float* out = (float*)d_out;

    char* ws = (char*)d_ws;
    size_t off = 0;
    auto alloc = [&](size_t bytes) { void* p = ws + off; off += (bytes + 255) & ~(size_t)255; return p; };
    _Float16* Wih16 = (_Float16*)alloc((size_t)NG * RR * 2);
    _Float16* Whh16 = (_Float16*)alloc((size_t)NG * HH * 2);
    _Float16* WhT16 = (_Float16*)alloc((size_t)DD * HH * 2);
    _Float16* xp16  = (_Float16*)alloc((size_t)1280 * RR * 2);
    _Float16* V16   = (_Float16*)alloc((size_t)TT * NB * RR * 2);
    _Float16* H16   = (_Float16*)alloc((size_t)TT * NB * HH * 2);
    float*    hbuf  = (float*)alloc((size_t)NB * HH * 4);
    float*    cb0   = (float*)alloc((size_t)NB * HH * 4);
    float*    cb1   = (float*)alloc((size_t)NB * HH * 4);
    _Float16* h16   = (_Float16*)alloc((size_t)NB * HH * 2);
    float*    gpart = (float*)alloc((size_t)8 * NB * NG * 4);
    _Float16* Wyu16 = (_Float16*)alloc((size_t)3 * KT * 2);
    float*    cstb  = (float*)alloc(16);
    if (ws_size < off) return;   // refuse to scribble out of bounds

    // one-time: weight conversion + Wh transpose + xproj + head fusion + init
    const int nconv = NG * RR + NG * HH;
    k_conv2<<<(nconv / 4 + 255) / 256, 256, 0, stream>>>(W_ih, Wih16, NG * RR,
                                                         W_hh, Whh16, NG * HH);
    k_whT<<<64, 256, 0, stream>>>(attn_Wh, WhT16);
    k_xproj<<<1280, 256, 0, stream>>>(feature, attn_Wx, xp16);
    k_wfuse<<<CHT + 1, 256, 0, stream>>>(Wy_w, Wh_w, Wu_w, Wh_b, Wu_b, Wyu16, cstb);
    k_init<<<64, 256, 0, stream>>>(feature, iWh_w, iWh_b, iWc_w, iWc_b, hbuf, cb0, h16);

    // attention for t=0 from h0
    k_step<<<dim3(64, 4), 512, 0, stream>>>(0, 0, gpart, b_ih, b_hh, cb0, cb1,
                                            h16, H16, hbuf, feature, xp16, WhT16,
                                            attn_v, V16);
    for (int t = 0; t < TT; ++t) {
        k_gates<<<512, 128, 0, stream>>>(t, V16, h16, Wih16, Whh16, gpart);
        const float* cin = (t & 1) ? cb1 : cb0;
        float* cou       = (t & 1) ? cb0 : cb1;
        k_step<<<dim3(64, 4), 512, 0, stream>>>(t + 1, 1, gpart, b_ih, b_hh, cin, cou,
                                                h16, H16, hbuf, feature, xp16, WhT16,
                                                attn_v, V16);
    }

    k_final2<<<1280, 256, 0, stream>>>(V16, H16, Wyu16, cstb, out);
}